// Round 10
// baseline (118.856 us; speedup 1.0000x reference)
//
#include <hip/hip_runtime.h>
#include <hip/hip_bf16.h>
#include <stdint.h>

#define D 128
#define MCOLS 196      // 14*14
#define XPITCH 232     // xc pitch (bf16)
#define BPITCH 136     // NS buffer pitch (bf16)
#define KOUT 8256      // 128*129/2

typedef short v8s __attribute__((ext_vector_type(8)));
typedef float v4f __attribute__((ext_vector_type(4)));

__device__ __forceinline__ uint32_t cvtpk(float a, float b) {
    __hip_bfloat162 h = __float22bfloat162_rn(make_float2(a, b));   // v_cvt_pk_bf16_f32
    uint32_t u;
    __builtin_memcpy(&u, &h, 4);
    return u;
}
__device__ __forceinline__ uint64_t pk64(float a, float b, float c, float d) {
    return (uint64_t)cvtpk(a, b) | ((uint64_t)cvtpk(c, d) << 32);
}
__device__ __forceinline__ float unlo(uint32_t u) { return __builtin_bit_cast(float, u << 16); }
__device__ __forceinline__ float unhi(uint32_t u) { return __builtin_bit_cast(float, u & 0xFFFF0000u); }

// Barrier WITHOUT vmcnt drain: keeps prefetch global_loads in flight across
// LDS-ordering barriers. lgkmcnt(0) orders all LDS ops; sched_barrier(0)
// prevents post-barrier ds ops hoisting above s_barrier.
__device__ __forceinline__ void barrier_nd() {
    asm volatile("s_waitcnt lgkmcnt(0)" ::: "memory");
    __builtin_amdgcn_s_barrier();
    __builtin_amdgcn_sched_barrier(0);
}

// Persistent: grid=256 (1 block/CU), 4 batches/block, batch k+1's input
// register-prefetched during batch k's NS chain. 1024 threads = 16 waves
// (4/SIMD); amdgpu_waves_per_eu(4,4) matches the LDS-capped occupancy so the
// allocator grants 128 VGPRs (default at 1024 thr is 64 -> R9 spilled).
// REGISTER-LEAN prefetch: f32 loads converted to packed bf16 EARLY (right
// after cov, HBM latency long past) -> only 14 regs live across the chain.
// cov runs on UNCENTERED bf16; exact f32 rank-1 mean fix (mean from f32 via
// shfl, double-buffered meanv). NS matrices symmetric -> one row-major LDS
// copy serves both MFMA operands; linear terms reloaded from own region.
__global__ __attribute__((amdgpu_waves_per_eu(4, 4))) __launch_bounds__(1024)
void mpncov_kernel(const float* __restrict__ x, float* __restrict__ out) {
    __shared__ __align__(16) uint16_t lds[4 * D * BPITCH];   // 139264 B
    __shared__ __align__(16) float meanv[2][D];
    __shared__ float redbuf[16];

    uint16_t* const B0 = lds;
    uint16_t* const B1 = lds + 1 * D * BPITCH;
    uint16_t* const B2 = lds + 2 * D * BPITCH;
    uint16_t* const B3 = lds + 3 * D * BPITCH;
    // xc (128 x 232 bf16 = 59392 B) overlays B1+B2 (69632 B). Rotation:
    // covM=B0, Y1=B1, ZY1=B2, Y2=B3, Z2=B1, T2=B0 -> B2 dead after MM4,
    // B1 dead after MM5 -> pack(k+1) runs during/after MM6.
    uint16_t (*const xc)[XPITCH] = reinterpret_cast<uint16_t(*)[XPITCH]>(B1);

    const int tid = threadIdx.x;
    const int lane = tid & 63;
    const int w = tid >> 6, wr = w >> 2, wc = w & 3;   // 4x4 wave grid
    const int lr = lane & 15, lk = lane >> 4;
    const int prow = tid >> 3, pq = tid & 7;           // prefetch: 8 threads/row

    // ---- cross-batch prefetch: 49 float4/row; f32 pf short-lived, bf16 pk persistent ----
    float4 pf[6]; float4 pfT;      // live: issue -> cvt (spans cov only)
    uint64_t pk[6]; uint64_t pkT;  // live: cvt -> pack (across NS chain, 14 regs)

    auto issue_pf = [&](int bbn) {
        const float4* p4 = reinterpret_cast<const float4*>(x + (size_t)bbn * (D * MCOLS)) + 49 * prow;
#pragma unroll
        for (int i = 0; i < 6; ++i) pf[i] = p4[pq + 8 * i];
        if (pq == 0) pfT = p4[48];
    };
    // f32 row-mean via 8-lane shfl (exact), store to meanv[nb]; pf -> pk (uncentered bf16)
    auto cvt_and_mean = [&](int nb) {
        float s = 0.f;
#pragma unroll
        for (int i = 0; i < 6; ++i) s += (pf[i].x + pf[i].y) + (pf[i].z + pf[i].w);
        if (pq == 0) s += (pfT.x + pfT.y) + (pfT.z + pfT.w);
        s += __shfl_xor(s, 1); s += __shfl_xor(s, 2); s += __shfl_xor(s, 4);
        if (pq == 0) meanv[nb][prow] = s * (1.0f / MCOLS);
#pragma unroll
        for (int i = 0; i < 6; ++i) pk[i] = pk64(pf[i].x, pf[i].y, pf[i].z, pf[i].w);
        if (pq == 0) pkT = pk64(pfT.x, pfT.y, pfT.z, pfT.w);
    };
    auto pack_pf = [&]() {   // scatter packed bf16 to xc + zero K-pad (cols 196..231)
#pragma unroll
        for (int i = 0; i < 6; ++i)
            *reinterpret_cast<uint64_t*>(&xc[prow][4 * (pq + 8 * i)]) = pk[i];
        if (pq == 0) *reinterpret_cast<uint64_t*>(&xc[prow][192]) = pkT;
        for (int idx = tid; idx < D * 9; idx += 1024) {
            const int row = idx / 9, p = idx - 9 * row;
            *reinterpret_cast<uint64_t*>(&xc[row][MCOLS + 4 * p]) = 0ull;
        }
    };

    v4f acc[2][2];
    auto zacc = [&]() {
#pragma unroll
        for (int i = 0; i < 2; ++i)
#pragma unroll
            for (int j = 0; j < 2; ++j) acc[i][j] = v4f{0.f, 0.f, 0.f, 0.f};
    };
    auto matmul = [&](const uint16_t* P, const uint16_t* Q) {
        zacc();
#pragma unroll
        for (int kk = 0; kk < 4; ++kk) {
            const int k0 = kk * 32 + lk * 8;
            v8s af[2], bf[2];
#pragma unroll
            for (int i = 0; i < 2; ++i)
                af[i] = *reinterpret_cast<const v8s*>(&P[(32 * wr + 16 * i + lr) * BPITCH + k0]);
#pragma unroll
            for (int j = 0; j < 2; ++j)
                bf[j] = *reinterpret_cast<const v8s*>(&Q[(32 * wc + 16 * j + lr) * BPITCH + k0]);
#pragma unroll
            for (int i = 0; i < 2; ++i)
#pragma unroll
                for (int j = 0; j < 2; ++j)
                    acc[i][j] = __builtin_amdgcn_mfma_f32_16x16x32_bf16(af[i], bf[j], acc[i][j], 0, 0, 0);
        }
    };
    auto store_tile = [&](uint16_t* dst, int i, int j, const v4f& v) {   // transposed b64
        const int r0 = 32 * wr + 16 * i + 4 * lk;
        const int c  = 32 * wc + 16 * j + lr;
        *reinterpret_cast<uint64_t*>(&dst[c * BPITCH + r0]) = pk64(v[0], v[1], v[2], v[3]);
    };
    auto own_addr = [&](const uint16_t* src, int i, int j) -> const uint64_t* {
        const int r0 = 32 * wr + 16 * i + 4 * lk;
        const int c  = 32 * wc + 16 * j + lr;
        return reinterpret_cast<const uint64_t*>(&src[c * BPITCH + r0]);
    };
    auto unq = [&](uint64_t g) -> v4f {
        return v4f{unlo((uint32_t)g), unhi((uint32_t)g),
                   unlo((uint32_t)(g >> 32)), unhi((uint32_t)(g >> 32))};
    };

    // Generic NS stage: dst = sAcc*(P@Q) + sO1*own1 [+ sO2*own2], own loads hoisted.
    auto stage = [&](const uint16_t* P, const uint16_t* Q, uint16_t* dst,
                     const uint16_t* own1, float sAcc, float sO1,
                     const uint16_t* own2, float sO2) {
        uint64_t g1[2][2], g2[2][2];
#pragma unroll
        for (int i = 0; i < 2; ++i)
#pragma unroll
            for (int j = 0; j < 2; ++j) {
                g1[i][j] = *own_addr(own1, i, j);
                if (own2) g2[i][j] = *own_addr(own2, i, j);
            }
        matmul(P, Q);
#pragma unroll
        for (int i = 0; i < 2; ++i)
#pragma unroll
            for (int j = 0; j < 2; ++j) {
                const v4f o1 = unq(g1[i][j]);
                v4f v;
#pragma unroll
                for (int q = 0; q < 4; ++q) v[q] = sAcc * acc[i][j][q] + sO1 * o1[q];
                if (own2) {
                    const v4f o2 = unq(g2[i][j]);
#pragma unroll
                    for (int q = 0; q < 4; ++q) v[q] += sO2 * o2[q];
                }
                store_tile(dst, i, j, v);
            }
    };

    // ---- prologue: stage batch (4*blockIdx.x); mean -> meanv[0] ----
    issue_pf(4 * blockIdx.x);
    cvt_and_mean(0);
    pack_pf();

    for (int it = 0; it < 4; ++it) {
        const int bb = 4 * blockIdx.x + it;
        const int cur = it & 1, nxt = cur ^ 1;
        barrier_nd();                               // xc(bb) + meanv[cur] ready

        if (it < 3) {                               // issue next batch's loads NOW
            issue_pf(bb + 1);
            __builtin_amdgcn_sched_barrier(0);
        }

        // ---- cov: covM = xc @ xc^T on UNCENTERED bf16 (K padded to 224) ----
        zacc();
#pragma unroll
        for (int kk = 0; kk < 7; ++kk) {
            const int k0 = kk * 32 + lk * 8;
            v8s af[2], bf[2];
#pragma unroll
            for (int i = 0; i < 2; ++i)
                af[i] = *reinterpret_cast<const v8s*>(&xc[32 * wr + 16 * i + lr][k0]);
#pragma unroll
            for (int j = 0; j < 2; ++j)
                bf[j] = *reinterpret_cast<const v8s*>(&xc[32 * wc + 16 * j + lr][k0]);
#pragma unroll
            for (int i = 0; i < 2; ++i)
#pragma unroll
                for (int j = 0; j < 2; ++j)
                    acc[i][j] = __builtin_amdgcn_mfma_f32_16x16x32_bf16(af[i], bf[j], acc[i][j], 0, 0, 0);
        }
        // exact f32 rank-1 centering fix: acc -= M * m_r * m_c
        {
            v4f mrow[2]; float mcol[2];
#pragma unroll
            for (int i = 0; i < 2; ++i)
                mrow[i] = *reinterpret_cast<const v4f*>(&meanv[cur][32 * wr + 16 * i + 4 * lk]);
#pragma unroll
            for (int j = 0; j < 2; ++j) mcol[j] = meanv[cur][32 * wc + 16 * j + lr];
#pragma unroll
            for (int i = 0; i < 2; ++i)
#pragma unroll
                for (int j = 0; j < 2; ++j)
#pragma unroll
                    for (int q = 0; q < 4; ++q)
                        acc[i][j][q] -= (float)MCOLS * mrow[i][q] * mcol[j];
        }

        // trace (C/D layout: col=lane&15, row=(lane>>4)*4+q)
        float tval = 0.f;
        if (wr == wc && (lr >> 2) == lk) {
            const int qq = lr & 3;
            tval = acc[0][0][qq] + acc[1][1][qq];
        }
#pragma unroll
        for (int off = 32; off; off >>= 1) tval += __shfl_down(tval, off);
        if (lane == 0) redbuf[w] = tval;

        // store covM (unnormalized; 1/tr folded into combine scalars below)
#pragma unroll
        for (int i = 0; i < 2; ++i)
#pragma unroll
            for (int j = 0; j < 2; ++j) store_tile(B0, i, j, acc[i][j]);

        if (it < 3) cvt_and_mean(nxt);              // pf(f32) -> pk(bf16); frees 14 regs
        barrier_nd();                               // covM + redbuf + meanv[nxt] visible; xc dead

        float tr = 0.f;
#pragma unroll
        for (int t = 0; t < 16; ++t) tr += redbuf[t];
        const float inv = 1.0f / tr;
        const float outscale = sqrtf(tr * (1.0f / MCOLS));

        // MM1: RY1 = -0.5*inv^2*(C@C) + 1.5*inv*C        -> B1
        stage(B0, B0, B1, B0, -0.5f * inv * inv, 1.5f * inv, nullptr, 0.f);
        barrier_nd();
        // MM2: RZY1 = 0.25*inv*(C@RY1) - 0.75*RY1        -> B2
        stage(B0, B1, B2, B1, 0.25f * inv, -0.75f, nullptr, 0.f);
        barrier_nd();
        // MM3: RY2 = RY1@RZY1 + 1.5*RY1                  -> B3
        stage(B1, B2, B3, B1, 1.f, 1.5f, nullptr, 0.f);
        barrier_nd();
        // MM4: RZ2 = -0.5*inv*(RZY1@C) - 0.75*inv*C + 1.5*RZY1  -> B1
        stage(B2, B0, B1, B0, -0.5f * inv, -0.75f * inv, B2, 1.5f);
        barrier_nd();
        // MM5: RT2 = RZ2@RY2 + 2.25*RY2                  -> B0
        stage(B1, B3, B0, B3, 1.f, 2.25f, nullptr, 0.f);
        barrier_nd();                              // T2 ready; B1,B2 (=xc region) dead

        // MM6: O = (1.5*RY2 - 0.5*(RY2@RT2)) * outscale ; upper-tri only
        if (wr <= wc) {
            uint64_t g[2][2];
#pragma unroll
            for (int i = 0; i < 2; ++i)
#pragma unroll
                for (int j = 0; j < 2; ++j) g[i][j] = *own_addr(B3, i, j);
            zacc();
#pragma unroll
            for (int kk = 0; kk < 4; ++kk) {
                const int k0 = kk * 32 + lk * 8;
                v8s af[2], bf[2];
#pragma unroll
                for (int i = 0; i < 2; ++i)
                    af[i] = *reinterpret_cast<const v8s*>(&B3[(32 * wr + 16 * i + lr) * BPITCH + k0]);
#pragma unroll
                for (int j = 0; j < 2; ++j)
                    bf[j] = *reinterpret_cast<const v8s*>(&B0[(32 * wc + 16 * j + lr) * BPITCH + k0]);
#pragma unroll
                for (int i = 0; i < 2; ++i)
#pragma unroll
                    for (int j = 0; j < 2; ++j)
                        if (2 * wr + i <= 2 * wc + j)
                            acc[i][j] = __builtin_amdgcn_mfma_f32_16x16x32_bf16(af[i], bf[j], acc[i][j], 0, 0, 0);
            }
            float* ob = out + (size_t)bb * KOUT;
#pragma unroll
            for (int i = 0; i < 2; ++i) {
                const int r0 = 32 * wr + 16 * i + 4 * lk;
#pragma unroll
                for (int j = 0; j < 2; ++j) {
                    const int rb = 2 * wr + i, cb = 2 * wc + j;
                    if (rb > cb) continue;
                    const int c = 32 * wc + 16 * j + lr;
                    const v4f o = unq(g[i][j]);
                    float vv[4];
#pragma unroll
                    for (int q = 0; q < 4; ++q)
                        vv[q] = (1.5f * o[q] - 0.5f * acc[i][j][q]) * outscale;
                    if (rb < cb) {
#pragma unroll
                        for (int q = 0; q < 4; ++q) {
                            const int r = r0 + q;
                            ob[r * D - (r * (r + 1)) / 2 + c] = vv[q];
                        }
                    } else {
#pragma unroll
                        for (int q = 0; q < 4; ++q) {
                            const int r = r0 + q;
                            if (r <= c) ob[r * D - (r * (r + 1)) / 2 + c] = vv[q];
                        }
                    }
                }
            }
        }
        if (it < 3) pack_pf();                     // xc(bb+1) into B1/B2, overlaps MM6
    }
}

extern "C" void kernel_launch(void* const* d_in, const int* in_sizes, int n_in,
                              void* d_out, int out_size, void* d_ws, size_t ws_size,
                              hipStream_t stream) {
    const float* x = (const float*)d_in[0];
    float* out = (float*)d_out;
    mpncov_kernel<<<dim3(256), dim3(1024), 0, stream>>>(x, out);
}

// Round 11
// 107.482 us; speedup vs baseline: 1.1058x; 1.1058x over previous
//
#include <hip/hip_runtime.h>
#include <hip/hip_bf16.h>
#include <stdint.h>

#define D 128
#define MCOLS 196      // 14*14
#define XPITCH 232     // xc pitch (bf16); row = 464B (16B-aligned)
#define BPITCH 136     // NS buffer pitch (bf16); row = 272B
#define KOUT 8256      // 128*129/2

typedef short v8s __attribute__((ext_vector_type(8)));
typedef float v4f __attribute__((ext_vector_type(4)));

__device__ __forceinline__ uint32_t cvtpk(float a, float b) {
    __hip_bfloat162 h = __float22bfloat162_rn(make_float2(a, b));   // v_cvt_pk_bf16_f32
    uint32_t u;
    __builtin_memcpy(&u, &h, 4);
    return u;
}
__device__ __forceinline__ uint64_t pk64(float a, float b, float c, float d) {
    return (uint64_t)cvtpk(a, b) | ((uint64_t)cvtpk(c, d) << 32);
}
__device__ __forceinline__ float unlo(uint32_t u) { return __builtin_bit_cast(float, u << 16); }
__device__ __forceinline__ float unhi(uint32_t u) { return __builtin_bit_cast(float, u & 0xFFFF0000u); }

// Barrier WITHOUT vmcnt drain: keeps prefetch global_loads in flight across
// LDS-ordering barriers. lgkmcnt(0) orders all LDS ops; sched_barrier(0)
// prevents post-barrier ds ops hoisting above s_barrier.
__device__ __forceinline__ void barrier_nd() {
    asm volatile("s_waitcnt lgkmcnt(0)" ::: "memory");
    __builtin_amdgcn_s_barrier();
    __builtin_amdgcn_sched_barrier(0);
}

// Persistent: grid=256 (1 block/CU), 4 batches/block, batch k+1's input
// register-prefetched during batch k's NS chain. 256 threads = 4 waves in a
// 2x2 grid, each wave owns a 64x64 region (4x4 16x16 tiles, acc[4][4]).
// 64x64 tiles minimize LDS read traffic (perimeter/area): 131KB/matmul vs
// 196KB at 64x32 (-33%). At 256-thread blocks the allocator budget is 256
// VGPRs (observed = 65536/block_threads) -> acc(64) + prefetch(100 f32,
// converted to 48 bf16 regs after MM2) fit with no spill.
// cov on UNCENTERED bf16 + exact f32 rank-1 mean fix (meanv double-buffered).
// NS matrices symmetric -> one row-major LDS copy serves both MFMA operands;
// linear terms c*R reloaded from wave-own region (transposed-contiguous b64).
__global__ __launch_bounds__(256) void mpncov_kernel(const float* __restrict__ x,
                                                     float* __restrict__ out) {
    __shared__ __align__(16) uint16_t lds[4 * D * BPITCH];   // 139264 B
    __shared__ __align__(16) float meanv[2][D];
    __shared__ float redbuf[4];

    uint16_t* const B0 = lds;
    uint16_t* const B1 = lds + 1 * D * BPITCH;
    uint16_t* const B2 = lds + 2 * D * BPITCH;
    uint16_t* const B3 = lds + 3 * D * BPITCH;
    // xc (128 x 232 bf16 = 59392 B) overlays B1+B2 (69632 B). Rotation:
    // covM=B0, Y1=B1, ZY1=B2, Y2=B3, Z2=B1, T2=B0 -> B2 dead after MM4,
    // B1 dead after MM5 -> pack(k+1) runs during/after MM6.
    uint16_t (*const xc)[XPITCH] = reinterpret_cast<uint16_t(*)[XPITCH]>(B1);

    const int tid = threadIdx.x;
    const int lane = tid & 63;
    const int w = tid >> 6, wr = w >> 1, wc = w & 1;   // 2x2 wave grid
    const int lr = lane & 15, lk = lane >> 4;
    const int prow = tid >> 1, h = tid & 1;            // prefetch: 2 threads/row

    // ---- cross-batch prefetch: 49 float4/row -> 24(+1) per thread ----
    float4 pf[24]; float4 pfT;     // f32, live issue -> cvt (cov+MM1+MM2)
    uint64_t pk[24]; uint64_t pkT; // bf16 packed, live cvt -> pack

    auto issue_pf = [&](int bbn) {
        const float4* p4 = reinterpret_cast<const float4*>(x + (size_t)bbn * (D * MCOLS)) + 49 * prow;
#pragma unroll
        for (int i = 0; i < 24; ++i) pf[i] = p4[24 * h + i];
        if (h == 0) pfT = p4[48];
    };
    // exact f32 row mean via 2-lane shfl -> meanv[nb]; pf -> pk (uncentered bf16)
    auto cvt_and_mean = [&](int nb) {
        float s = 0.f;
#pragma unroll
        for (int i = 0; i < 24; ++i) s += (pf[i].x + pf[i].y) + (pf[i].z + pf[i].w);
        if (h == 0) s += (pfT.x + pfT.y) + (pfT.z + pfT.w);
        s += __shfl_xor(s, 1);
        if (h == 0) meanv[nb][prow] = s * (1.0f / MCOLS);
#pragma unroll
        for (int i = 0; i < 24; ++i) pk[i] = pk64(pf[i].x, pf[i].y, pf[i].z, pf[i].w);
        if (h == 0) pkT = pk64(pfT.x, pfT.y, pfT.z, pfT.w);
    };
    auto pack_pf = [&]() {   // scatter packed bf16 to xc + zero K-pad (cols 196..231)
#pragma unroll
        for (int i = 0; i < 24; ++i)
            *reinterpret_cast<uint64_t*>(&xc[prow][4 * (24 * h + i)]) = pk[i];
        if (h == 0) *reinterpret_cast<uint64_t*>(&xc[prow][192]) = pkT;
        for (int idx = tid; idx < D * 9; idx += 256) {
            const int row = idx / 9, p = idx - 9 * row;
            *reinterpret_cast<uint64_t*>(&xc[row][MCOLS + 4 * p]) = 0ull;
        }
    };

    v4f acc[4][4];
    auto zacc = [&]() {
#pragma unroll
        for (int i = 0; i < 4; ++i)
#pragma unroll
            for (int j = 0; j < 4; ++j) acc[i][j] = v4f{0.f, 0.f, 0.f, 0.f};
    };
    auto matmul = [&](const uint16_t* P, const uint16_t* Q) {
        zacc();
#pragma unroll
        for (int kk = 0; kk < 4; ++kk) {
            const int k0 = kk * 32 + lk * 8;
            v8s af[4], bf[4];
#pragma unroll
            for (int i = 0; i < 4; ++i)
                af[i] = *reinterpret_cast<const v8s*>(&P[(64 * wr + 16 * i + lr) * BPITCH + k0]);
#pragma unroll
            for (int j = 0; j < 4; ++j)
                bf[j] = *reinterpret_cast<const v8s*>(&Q[(64 * wc + 16 * j + lr) * BPITCH + k0]);
#pragma unroll
            for (int i = 0; i < 4; ++i)
#pragma unroll
                for (int j = 0; j < 4; ++j)
                    acc[i][j] = __builtin_amdgcn_mfma_f32_16x16x32_bf16(af[i], bf[j], acc[i][j], 0, 0, 0);
        }
    };
    auto store_tile = [&](uint16_t* dst, int i, int j, const v4f& v) {   // transposed b64
        const int r0 = 64 * wr + 16 * i + 4 * lk;
        const int c  = 64 * wc + 16 * j + lr;
        *reinterpret_cast<uint64_t*>(&dst[c * BPITCH + r0]) = pk64(v[0], v[1], v[2], v[3]);
    };
    auto own_addr = [&](const uint16_t* src, int i, int j) -> const uint64_t* {
        const int r0 = 64 * wr + 16 * i + 4 * lk;
        const int c  = 64 * wc + 16 * j + lr;
        return reinterpret_cast<const uint64_t*>(&src[c * BPITCH + r0]);
    };
    auto unq = [&](uint64_t g) -> v4f {
        return v4f{unlo((uint32_t)g), unhi((uint32_t)g),
                   unlo((uint32_t)(g >> 32)), unhi((uint32_t)(g >> 32))};
    };

    // Generic NS stage: dst = sAcc*(P@Q) + sO1*own1 [+ sO2*own2], own loads hoisted.
    auto stage = [&](const uint16_t* P, const uint16_t* Q, uint16_t* dst,
                     const uint16_t* own1, float sAcc, float sO1,
                     const uint16_t* own2, float sO2) {
        uint64_t g1[4][4], g2[4][4];
#pragma unroll
        for (int i = 0; i < 4; ++i)
#pragma unroll
            for (int j = 0; j < 4; ++j) {
                g1[i][j] = *own_addr(own1, i, j);
                if (own2) g2[i][j] = *own_addr(own2, i, j);
            }
        matmul(P, Q);
#pragma unroll
        for (int i = 0; i < 4; ++i)
#pragma unroll
            for (int j = 0; j < 4; ++j) {
                const v4f o1 = unq(g1[i][j]);
                v4f v;
#pragma unroll
                for (int q = 0; q < 4; ++q) v[q] = sAcc * acc[i][j][q] + sO1 * o1[q];
                if (own2) {
                    const v4f o2 = unq(g2[i][j]);
#pragma unroll
                    for (int q = 0; q < 4; ++q) v[q] += sO2 * o2[q];
                }
                store_tile(dst, i, j, v);
            }
    };

    // ---- prologue: stage batch (4*blockIdx.x); mean -> meanv[0] ----
    issue_pf(4 * blockIdx.x);
    cvt_and_mean(0);
    pack_pf();

    for (int it = 0; it < 4; ++it) {
        const int bb = 4 * blockIdx.x + it;
        const int cur = it & 1, nxt = cur ^ 1;
        barrier_nd();                               // xc(bb) + meanv[cur] ready

        if (it < 3) {                               // issue next batch's loads NOW
            issue_pf(bb + 1);
            __builtin_amdgcn_sched_barrier(0);
        }

        // ---- cov: covM = xc @ xc^T on UNCENTERED bf16 (K padded to 224) ----
        zacc();
#pragma unroll
        for (int kk = 0; kk < 7; ++kk) {
            const int k0 = kk * 32 + lk * 8;
            v8s af[4], bf[4];
#pragma unroll
            for (int i = 0; i < 4; ++i)
                af[i] = *reinterpret_cast<const v8s*>(&xc[64 * wr + 16 * i + lr][k0]);
#pragma unroll
            for (int j = 0; j < 4; ++j)
                bf[j] = *reinterpret_cast<const v8s*>(&xc[64 * wc + 16 * j + lr][k0]);
#pragma unroll
            for (int i = 0; i < 4; ++i)
#pragma unroll
                for (int j = 0; j < 4; ++j)
                    acc[i][j] = __builtin_amdgcn_mfma_f32_16x16x32_bf16(af[i], bf[j], acc[i][j], 0, 0, 0);
        }
        // exact f32 rank-1 centering fix: acc -= M * m_r * m_c
        {
            v4f mrow[4]; float mcol[4];
#pragma unroll
            for (int i = 0; i < 4; ++i)
                mrow[i] = *reinterpret_cast<const v4f*>(&meanv[cur][64 * wr + 16 * i + 4 * lk]);
#pragma unroll
            for (int j = 0; j < 4; ++j) mcol[j] = meanv[cur][64 * wc + 16 * j + lr];
#pragma unroll
            for (int i = 0; i < 4; ++i)
#pragma unroll
                for (int j = 0; j < 4; ++j)
#pragma unroll
                    for (int q = 0; q < 4; ++q)
                        acc[i][j][q] -= (float)MCOLS * mrow[i][q] * mcol[j];
        }

        // trace (C/D layout: col=lane&15, row=(lane>>4)*4+q)
        float tval = 0.f;
        if (wr == wc && (lr >> 2) == lk) {
            const int qq = lr & 3;
#pragma unroll
            for (int i = 0; i < 4; ++i) tval += acc[i][i][qq];
        }
#pragma unroll
        for (int off = 32; off; off >>= 1) tval += __shfl_down(tval, off);
        if (wr == wc && lane == 0) redbuf[w] = tval;

        // store covM (unnormalized; 1/tr folded into combine scalars below)
#pragma unroll
        for (int i = 0; i < 4; ++i)
#pragma unroll
            for (int j = 0; j < 4; ++j) store_tile(B0, i, j, acc[i][j]);
        barrier_nd();                               // covM + redbuf visible; xc dead

        const float tr = (redbuf[0] + redbuf[3]);   // waves 0 (wr=wc=0) and 3 (wr=wc=1)
        const float inv = 1.0f / tr;
        const float outscale = sqrtf(tr * (1.0f / MCOLS));

        // MM1: RY1 = -0.5*inv^2*(C@C) + 1.5*inv*C        -> B1
        stage(B0, B0, B1, B0, -0.5f * inv * inv, 1.5f * inv, nullptr, 0.f);
        barrier_nd();
        // MM2: RZY1 = 0.25*inv*(C@RY1) - 0.75*RY1        -> B2
        stage(B0, B1, B2, B1, 0.25f * inv, -0.75f, nullptr, 0.f);
        if (it < 3) cvt_and_mean(nxt);             // loads landed (~2 stages ago); frees 52 regs
        barrier_nd();
        // MM3: RY2 = RY1@RZY1 + 1.5*RY1                  -> B3
        stage(B1, B2, B3, B1, 1.f, 1.5f, nullptr, 0.f);
        barrier_nd();
        // MM4: RZ2 = -0.5*inv*(RZY1@C) - 0.75*inv*C + 1.5*RZY1  -> B1
        stage(B2, B0, B1, B0, -0.5f * inv, -0.75f * inv, B2, 1.5f);
        barrier_nd();
        // MM5: RT2 = RZ2@RY2 + 2.25*RY2                  -> B0
        stage(B1, B3, B0, B3, 1.f, 2.25f, nullptr, 0.f);
        barrier_nd();                              // T2 ready; B1,B2 (=xc region) dead

        // MM6: O = (1.5*RY2 - 0.5*(RY2@RT2)) * outscale ; upper-tri only
        if (!(wr == 1 && wc == 0)) {
            uint64_t g[4][4];
#pragma unroll
            for (int i = 0; i < 4; ++i)
#pragma unroll
                for (int j = 0; j < 4; ++j) g[i][j] = *own_addr(B3, i, j);
            zacc();
#pragma unroll
            for (int kk = 0; kk < 4; ++kk) {
                const int k0 = kk * 32 + lk * 8;
                v8s af[4], bf[4];
#pragma unroll
                for (int i = 0; i < 4; ++i)
                    af[i] = *reinterpret_cast<const v8s*>(&B3[(64 * wr + 16 * i + lr) * BPITCH + k0]);
#pragma unroll
                for (int j = 0; j < 4; ++j)
                    bf[j] = *reinterpret_cast<const v8s*>(&B0[(64 * wc + 16 * j + lr) * BPITCH + k0]);
#pragma unroll
                for (int i = 0; i < 4; ++i)
#pragma unroll
                    for (int j = 0; j < 4; ++j)
                        if (4 * wr + i <= 4 * wc + j)
                            acc[i][j] = __builtin_amdgcn_mfma_f32_16x16x32_bf16(af[i], bf[j], acc[i][j], 0, 0, 0);
            }
            float* ob = out + (size_t)bb * KOUT;
#pragma unroll
            for (int i = 0; i < 4; ++i) {
                const int r0 = 64 * wr + 16 * i + 4 * lk;
#pragma unroll
                for (int j = 0; j < 4; ++j) {
                    const int rb = 4 * wr + i, cb = 4 * wc + j;
                    if (rb > cb) continue;
                    const int c = 64 * wc + 16 * j + lr;
                    const v4f o = unq(g[i][j]);
                    float vv[4];
#pragma unroll
                    for (int q = 0; q < 4; ++q)
                        vv[q] = (1.5f * o[q] - 0.5f * acc[i][j][q]) * outscale;
                    if (rb < cb) {
#pragma unroll
                        for (int q = 0; q < 4; ++q) {
                            const int r = r0 + q;
                            ob[r * D - (r * (r + 1)) / 2 + c] = vv[q];
                        }
                    } else {
#pragma unroll
                        for (int q = 0; q < 4; ++q) {
                            const int r = r0 + q;
                            if (r <= c) ob[r * D - (r * (r + 1)) / 2 + c] = vv[q];
                        }
                    }
                }
            }
        }
        if (it < 3) pack_pf();                     // xc(bb+1) into B1/B2, overlaps MM6
    }
}

extern "C" void kernel_launch(void* const* d_in, const int* in_sizes, int n_in,
                              void* d_out, int out_size, void* d_ws, size_t ws_size,
                              hipStream_t stream) {
    const float* x = (const float*)d_in[0];
    float* out = (float*)d_out;
    mpncov_kernel<<<dim3(256), dim3(256), 0, stream>>>(x, out);
}